// Round 13
// baseline (85.043 us; speedup 1.0000x reference)
//
#include <hip/hip_runtime.h>

typedef float v2f __attribute__((ext_vector_type(2)));
typedef float v4f __attribute__((ext_vector_type(4)));

#define IMG 512
#define NBLK 512              // 64x64 tile per block: 8 x 8 tiles x 8 images

// LDS layouts (floats)
#define A_STR  92             // h tile [84][92]; gy=y0-10+r, gx=x0-12+c (c 0..87 used)
#define BT_STR 74             // BT [88][74]: BT[c][by], by 0..73 (gy=y0-5+by)
#define ET_STR 76             // ET [74][76]: ET[ex][ey]; gx=x0-5+ex, gy=y0-5+ey; overlays Abuf
#define CT_STR 68             // CT [74][68]: CT[ex][oy], oy 0..63; overlays Bbuf

__device__ __forceinline__ v2f lo2(v4f v) { return __builtin_shufflevector(v, v, 0, 1); }
__device__ __forceinline__ v2f hi2(v4f v) { return __builtin_shufflevector(v, v, 2, 3); }

// one float4 of the h halo tile (zero-padded), quad index idx in [0,1848): 84 rows x 22 quads
__device__ __forceinline__ v4f ldq(const float* __restrict__ hmap, size_t base,
                                   int x0, int y0, int idx) {
    int r = idx / 22, q = idx - r * 22;
    int gy = y0 - 10 + r, gx0 = x0 - 12 + 4 * q;
    v4f v = {0.f, 0.f, 0.f, 0.f};
    if ((unsigned)gy < IMG) {
        const float* hr = &hmap[base + ((size_t)gy << 9)];
        if (gx0 >= 0 && gx0 + 3 < IMG) {
            v = *(const v4f*)&hr[gx0];
        } else {
            if ((unsigned)(gx0 + 0) < IMG) v.x = hr[gx0 + 0];
            if ((unsigned)(gx0 + 1) < IMG) v.y = hr[gx0 + 1];
            if ((unsigned)(gx0 + 2) < IMG) v.z = hr[gx0 + 2];
            if ((unsigned)(gx0 + 3) < IMG) v.w = hr[gx0 + 3];
        }
    }
    return v;
}

__global__ __launch_bounds__(256, 2) void marl_fused(
    const float* __restrict__ prob,
    const float* __restrict__ cmap,
    const float* __restrict__ hmap,
    float* __restrict__ ws)
{
    __shared__ __align__(16) float Abuf[84 * A_STR];   // 7728 f: h tile, then ET[74][76]
    __shared__ __align__(16) float Bbuf[88 * BT_STR];  // 6512 f: BT, then CT[74][68]
    __shared__ float red[4];

    const float W[11] = {0.00881223f, 0.02714358f, 0.06511405f, 0.12164908f,
                         0.17699840f, 0.20056540f, 0.17699840f, 0.12164908f,
                         0.06511405f, 0.02714358f, 0.00881223f};
    v2f wv[11];
#pragma unroll
    for (int i = 0; i < 11; ++i) wv[i] = (v2f){W[i], W[i]};
    float w2 = 0.f;
#pragma unroll
    for (int i = 0; i < 11; ++i) w2 += W[i] * W[i];
    const float sumk2 = w2 * w2;
    const v2f z = {0.f, 0.f};

    const int tid = threadIdx.x;
    // tile decode: 64 tiles/image (8 x 8), 64x64 outputs
    const int T  = blockIdx.x;
    const int b  = T >> 6, r6 = T & 63;
    const int x0 = (r6 & 7) << 6, y0 = (r6 >> 3) << 6;
    const size_t base = (size_t)b << 18;

    // P1: 242 workers: run = tid%11 (by0 = 7*run), q = tid/11 (col-quad 0..21)
    const int p1run = tid % 11, p1q = tid / 11;
    // P2: 185 workers: p = tid%37 (ey-pair), g = tid/37 (ex-16 group 0..4)
    const int p2p = tid % 37, p2g = tid / 37;
    // P4: 256 workers: ox0 = 8*(tid>>5), oy0e = 2*(tid&31)
    const int ox0 = (tid >> 5) << 3, oy0e = (tid & 31) << 1;

    // ---- prologue: stage h tile (84x88 used) to LDS; c + epilogue h/prob to regs ----
    float creg[2][16];
    v4f hqa[2], hqb[2], pqa[2], pqb[2];
    {
        v4f st[8];
#pragma unroll
        for (int k = 0; k < 7; ++k) st[k] = ldq(hmap, base, x0, y0, tid + 256 * k);
        st[7] = (tid < 56) ? ldq(hmap, base, x0, y0, tid + 1792) : (v4f){0.f,0.f,0.f,0.f};
        if (tid < 185) {
#pragma unroll
            for (int h = 0; h < 2; ++h) {
                int gy = y0 - 5 + 2 * p2p + h;
                bool yin = (unsigned)gy < IMG;
                const float* cr = &cmap[base + ((size_t)gy << 9)];
#pragma unroll
                for (int c = 0; c < 16; ++c) {
                    int gx = x0 - 5 + 16 * p2g + c;
                    creg[h][c] = (yin && (unsigned)gx < IMG) ? cr[gx] : 0.f;
                }
            }
        }
#pragma unroll
        for (int h = 0; h < 2; ++h) {
            size_t rowb = base + ((size_t)(y0 + oy0e + h) << 9) + (x0 + ox0);
            hqa[h] = *(const v4f*)&hmap[rowb];
            hqb[h] = *(const v4f*)&hmap[rowb + 4];
            pqa[h] = *(const v4f*)&prob[rowb];
            pqb[h] = *(const v4f*)&prob[rowb + 4];
        }
#pragma unroll
        for (int k = 0; k < 7; ++k) {
            int idx = tid + 256 * k;
            int r = idx / 22, q = idx - r * 22;
            *(v4f*)&Abuf[r * A_STR + 4 * q] = st[k];
        }
        if (tid < 56) {
            int idx = tid + 1792;
            int r = idx / 22, q = idx - r * 22;
            *(v4f*)&Abuf[r * A_STR + 4 * q] = st[7];
        }
    }
    __syncthreads();

    // ---- P1: convY(h): Abuf[84][92] -> BT[88][74], 7 outs/worker ----
    if (tid < 242) {
        int by0 = 7 * p1run;
        v2f accLo[7] = {z, z, z, z, z, z, z}, accHi[7] = {z, z, z, z, z, z, z};
#pragma unroll
        for (int i = 0; i < 17; ++i) {
            int rr = by0 + i; rr = rr > 83 ? 83 : rr;   // clamp: clipped outs discard
            v4f a = *(const v4f*)&Abuf[rr * A_STR + 4 * p1q];
            v2f lo = lo2(a), hi = hi2(a);
#pragma unroll
            for (int r = 0; r < 7; ++r) {
                int j = i - r;
                if (j >= 0 && j < 11) { accLo[r] += wv[j] * lo; accHi[r] += wv[j] * hi; }
            }
        }
#pragma unroll
        for (int r = 0; r < 7; ++r) {
            int by = by0 + r;
            if (by < 74) {
                Bbuf[(4 * p1q + 0) * BT_STR + by] = accLo[r].x;
                Bbuf[(4 * p1q + 1) * BT_STR + by] = accLo[r].y;
                Bbuf[(4 * p1q + 2) * BT_STR + by] = accHi[r].x;
                Bbuf[(4 * p1q + 3) * BT_STR + by] = accHi[r].y;
            }
        }
    }
    __syncthreads();

    // ---- P2: convX(BT) - c(regs) -> ET[74][76] (overlays Abuf), 16 cols/worker ----
    if (tid < 185) {
        int ex0 = 16 * p2g, ey0 = 2 * p2p;
        v2f acc[16] = {z, z, z, z, z, z, z, z, z, z, z, z, z, z, z, z};
#pragma unroll
        for (int i = 0; i < 26; ++i) {
            int cb = ex0 + 2 + i; cb = cb > 87 ? 87 : cb;   // clamp: clipped outs discard
            v2f bb = *(const v2f*)&Bbuf[cb * BT_STR + ey0];
#pragma unroll
            for (int c = 0; c < 16; ++c) {
                int j = i - c;
                if (j >= 0 && j < 11) acc[c] += wv[j] * bb;
            }
        }
#pragma unroll
        for (int c = 0; c < 16; ++c) {
            int ex = ex0 + c;
            if (ex < 74) {
                int gx = x0 - 5 + ex;
                bool xin = (unsigned)gx < IMG;
                v2f ev;
#pragma unroll
                for (int h = 0; h < 2; ++h) {
                    int gy = y0 - 5 + ey0 + h;
                    ev[h] = (xin && (unsigned)gy < IMG) ? acc[c][h] - creg[h][c] : 0.f;
                }
                *(v2f*)&Abuf[ex * ET_STR + ey0] = ev;
            }
        }
    }
    __syncthreads();

    // ---- P3: convY(ET) via register window -> CT[74][68], 16 outs/worker ----
    // 296 work items (74 ex x 4 oy-quarters); grid-stride x2 over 256 threads
#pragma unroll
    for (int w = tid; w < 296; w += 256) {
        int wex = w % 74, woyq = w / 74;
        int oy0 = 16 * woyq;
        const float* src = &Abuf[wex * ET_STR + oy0];
        float win[26];
#pragma unroll
        for (int k = 0; k < 6; ++k)
            *(v4f*)&win[4 * k] = *(const v4f*)&src[4 * k];
        *(v2f*)&win[24] = *(const v2f*)&src[24];
        float o[16];
#pragma unroll
        for (int k = 0; k < 16; ++k) {
            float acc = 0.f;
#pragma unroll
            for (int j = 0; j < 11; ++j) acc += W[j] * win[k + j];
            o[k] = acc;
        }
#pragma unroll
        for (int k = 0; k < 4; ++k)
            *(v4f*)&Bbuf[wex * CT_STR + oy0 + 4 * k] =
                (v4f){o[4 * k], o[4 * k + 1], o[4 * k + 2], o[4 * k + 3]};
    }
    __syncthreads();

    // ---- P4: convX(CT) -> corr + fused epilogue (256 workers, 16 outs each) ----
    float partial = 0.f;
    {
        v2f acc[8] = {z, z, z, z, z, z, z, z};
#pragma unroll
        for (int i = 0; i < 18; ++i) {
            v2f ct = *(const v2f*)&Bbuf[(ox0 + i) * CT_STR + oy0e];
#pragma unroll
            for (int c = 0; c < 8; ++c) {
                int j = i - c;
                if (j >= 0 && j < 11) acc[c] += wv[j] * ct;
            }
        }
#pragma unroll
        for (int h = 0; h < 2; ++h) {
#pragma unroll
            for (int c = 0; c < 8; ++c) {
                float h_ = (c < 4) ? hqa[h][c] : hqb[h][c - 4];
                float p_ = (c < 4) ? pqa[h][c] : pqb[h][c - 4];
                float logp = __logf(h_ > 0.5f ? p_ + 1e-8f : 1.f - p_ + 1e-8f);
                float delta = 1.f - 2.f * h_;
                partial += (2.f * delta * acc[c][h] + sumk2) * logp;
            }
        }
    }

    // ---- reduction -> per-block partial in ws ----
#pragma unroll
    for (int off = 32; off > 0; off >>= 1)
        partial += __shfl_down(partial, off, 64);
    if ((tid & 63) == 0) red[tid >> 6] = partial;
    __syncthreads();
    if (tid == 0)
        ws[blockIdx.x] = red[0] + red[1] + red[2] + red[3];
}

__global__ __launch_bounds__(256) void marl_reduce(const float* __restrict__ ws,
                                                   float* __restrict__ out)
{
    __shared__ float red[4];
    const int tid = threadIdx.x;
    float s = ws[tid] + ws[tid + 256];
#pragma unroll
    for (int off = 32; off > 0; off >>= 1)
        s += __shfl_down(s, off, 64);
    if ((tid & 63) == 0) red[tid >> 6] = s;
    __syncthreads();
    if (tid == 0)
        out[0] = -0.125f * (red[0] + red[1] + red[2] + red[3]);  // loss = -sum / B
}

extern "C" void kernel_launch(void* const* d_in, const int* in_sizes, int n_in,
                              void* d_out, int out_size, void* d_ws, size_t ws_size,
                              hipStream_t stream) {
    const float* prob = (const float*)d_in[0];
    const float* cmap = (const float*)d_in[1];
    const float* hmap = (const float*)d_in[2];
    float* out = (float*)d_out;
    float* ws  = (float*)d_ws;

    marl_fused<<<dim3(NBLK), dim3(256), 0, stream>>>(prob, cmap, hmap, ws);
    marl_reduce<<<dim3(1), dim3(256), 0, stream>>>(ws, out);
}